// Round 14
// baseline (285.414 us; speedup 1.0000x reference)
//
#include <hip/hip_runtime.h>
#include <hip/hip_bf16.h>
#include <stdint.h>

typedef __attribute__((ext_vector_type(16))) float f32x16;
typedef __attribute__((ext_vector_type(8))) short short8;

__device__ __forceinline__ ushort f2b(float f) {
    union { __hip_bfloat16 h; ushort u; } c;
    c.h = __float2bfloat16(f);
    return c.u;
}

// async global->LDS, 16B per lane. LDS dest is wave-uniform; HW adds lane*16.
__device__ __forceinline__ void gload_lds16(const void* g, void* lds) {
    __builtin_amdgcn_global_load_lds((const __attribute__((address_space(1))) void*)g,
                                     (__attribute__((address_space(3))) void*)lds,
                                     16, 0, 0);
}

#define BARRIER()  asm volatile("s_barrier" ::: "memory")
#define VMCNT4()   asm volatile("s_waitcnt vmcnt(4)" ::: "memory")

// ---- fused pre-pass: x -> bf16 (y==0), w * blockscale -> bf16 (y==1) --------
__global__ void conv_both_kernel(const float* __restrict__ x, ushort* __restrict__ xb, long n8x,
                                 const float* __restrict__ w, const float* __restrict__ sinv,
                                 ushort* __restrict__ wb, int K, int nbk, long n8w) {
    long i = (long)blockIdx.x * blockDim.x + threadIdx.x;
    if (blockIdx.y == 0) {
        if (i >= n8x) return;
        const float4* xv = (const float4*)x;
        float4 v0 = xv[i * 2], v1 = xv[i * 2 + 1];
        short8 r;
        r[0] = (short)f2b(v0.x); r[1] = (short)f2b(v0.y); r[2] = (short)f2b(v0.z); r[3] = (short)f2b(v0.w);
        r[4] = (short)f2b(v1.x); r[5] = (short)f2b(v1.y); r[6] = (short)f2b(v1.z); r[7] = (short)f2b(v1.w);
        *(short8*)&xb[i * 8] = r;
    } else {
        if (i >= n8w) return;
        long e = i * 8;
        int o, c;
        if (K == 4096) { o = (int)(e >> 12); c = (int)(e & 4095); }
        else { o = (int)(e / K); c = (int)(e - (long)o * K); }
        const float s = sinv[(o >> 7) * nbk + (c >> 7)];
        const float4* wv = (const float4*)(w + e);
        float4 v0 = wv[0], v1 = wv[1];
        short8 r;
        r[0] = (short)f2b(v0.x * s); r[1] = (short)f2b(v0.y * s); r[2] = (short)f2b(v0.z * s); r[3] = (short)f2b(v0.w * s);
        r[4] = (short)f2b(v1.x * s); r[5] = (short)f2b(v1.y * s); r[6] = (short)f2b(v1.z * s); r[7] = (short)f2b(v1.w * s);
        *(short8*)&wb[e] = r;
    }
}

// ---- main GEMM: 256x256 tile, BK=64, 8 waves (2Mx4N), 32x32x16 MFMA ---------
// 2 phases per K-tile, 16 MFMA/phase, carried kh-fragments + embedded
// next-kh reads + cross-tile pre-read. Stage map: P0(t)->(t+1).K1->nb,
// P1(t)->(t+2).K0->b; uniform vmcnt(4) per phase (never 0).
// LDS: [buf][op][kh][256 rows][32 shorts], chunk ^= (row>>1)&3.
__global__ __launch_bounds__(512, 2)
void gemm256_kernel(const ushort* __restrict__ A, const ushort* __restrict__ Bm,
                    const float* __restrict__ bias, float* __restrict__ C,
                    int M, int N, int K) {
    __shared__ alignas(16) short sm[2][32768];  // [buf][ A: kh*8192+row*32 | B: +16384 ]

    const int tid  = threadIdx.x;
    const int lane = tid & 63;
    const int wid  = tid >> 6;
    const int wr   = wid >> 2;          // 0..1  -> 128-row slice of C
    const int wc   = wid & 3;           // 0..3  -> 64-col slice of C
    const int nbn  = N >> 8;

    // XCD-aware bijective swizzle (launcher guarantees gridDim.x % 8 == 0)
    const int nwg = gridDim.x;
    const int swz = (blockIdx.x & 7) * (nwg >> 3) + (blockIdx.x >> 3);
    const int bm  = swz / nbn;
    const int bn  = swz % nbn;

    const short* gA = (const short*)A + (size_t)bm * 256 * K;
    const short* gB = (const short*)Bm + (size_t)bn * 256 * K;

    // stage one K-half (256 rows x 32 cols, 16KB): thread -> 2 gloads.
    auto STAGE = [&](const short* gOp, int opOff, int kh, int kt, int buf) {
#pragma unroll
        for (int g = 0; g < 2; ++g) {
            int R = wid * 32 + g * 16 + (lane >> 2);
            int chunk = (lane & 3) ^ ((R >> 1) & 3);
            const short* src = gOp + (size_t)R * K + kt * 64 + kh * 32 + chunk * 8;
            gload_lds16(src, &sm[buf][opOff + kh * 8192 + wid * 1024 + g * 512]);
        }
    };

    // 32x32x16 fragment reads. A: row = lane&31 of m-tile, k = (lane>>5)*8+j.
    // s = k-step within half (0|1). chunk = (s*2 + (lane>>5)) ^ ((row>>1)&3).
    auto LD_A32 = [&](int buf, int kh, int s, int mt, short8& a) {
        int row = wr * 128 + mt * 32 + (lane & 31);
        int chunk = ((s << 1) + (lane >> 5)) ^ ((row >> 1) & 3);
        a = *(const short8*)&sm[buf][kh * 8192 + row * 32 + (chunk << 3)];
    };
    auto LD_B32 = [&](int buf, int kh, int s, int nt, short8& bfr) {
        int row = wc * 64 + nt * 32 + (lane & 31);
        int chunk = ((s << 1) + (lane >> 5)) ^ ((row >> 1) & 3);
        bfr = *(const short8*)&sm[buf][16384 + kh * 8192 + row * 32 + (chunk << 3)];
    };

    f32x16 acc[4][2] = {};

    const int nkt = K >> 6;   // >= 32, even (launcher enforces K % 2048 == 0)

    short8 aCur[2][4], bCur[2][2];   // current kh fragments (s, mt/nt)

    // One phase: 16 MFMA on (aU,bU); fill (aV,bV) from (fb,fkh) interleaved.
    auto PHASE = [&](short8 (&aU)[2][4], short8 (&bU)[2][2],
                     int fb, int fkh, short8 (&aV)[2][4], short8 (&bV)[2][2]) {
        __builtin_amdgcn_s_setprio(1);
        // s=0, mt 0..1
#pragma unroll
        for (int mt = 0; mt < 2; ++mt)
#pragma unroll
            for (int nt = 0; nt < 2; ++nt)
                acc[mt][nt] = __builtin_amdgcn_mfma_f32_32x32x16_bf16(aU[0][mt], bU[0][nt], acc[mt][nt], 0, 0, 0);
        // fill s=0 of next
#pragma unroll
        for (int mt = 0; mt < 4; ++mt) LD_A32(fb, fkh, 0, mt, aV[0][mt]);
#pragma unroll
        for (int nt = 0; nt < 2; ++nt) LD_B32(fb, fkh, 0, nt, bV[0][nt]);
        // s=0, mt 2..3
#pragma unroll
        for (int mt = 2; mt < 4; ++mt)
#pragma unroll
            for (int nt = 0; nt < 2; ++nt)
                acc[mt][nt] = __builtin_amdgcn_mfma_f32_32x32x16_bf16(aU[0][mt], bU[0][nt], acc[mt][nt], 0, 0, 0);
        // fill s=1 of next
#pragma unroll
        for (int mt = 0; mt < 4; ++mt) LD_A32(fb, fkh, 1, mt, aV[1][mt]);
#pragma unroll
        for (int nt = 0; nt < 2; ++nt) LD_B32(fb, fkh, 1, nt, bV[1][nt]);
        // s=1, all
#pragma unroll
        for (int mt = 0; mt < 4; ++mt)
#pragma unroll
            for (int nt = 0; nt < 2; ++nt)
                acc[mt][nt] = __builtin_amdgcn_mfma_f32_32x32x16_bf16(aU[1][mt], bU[1][nt], acc[mt][nt], 0, 0, 0);
        __builtin_amdgcn_s_setprio(0);
    };

    auto KSTEP = [&](int t) {
        const int b  = t & 1;
        const int nb = b ^ 1;
        const int t1 = (t + 1 < nkt) ? t + 1 : nkt - 1;
        const int t2 = (t + 2 < nkt) ? t + 2 : nkt - 1;

        short8 aN[2][4], bN[2][2];

        // ---- P0: MFMA (t).kh0; fill (t).kh1 from b; stage (t+1).K1 -> nb ----
        BARRIER();
        PHASE(aCur, bCur, b, 1, aN, bN);
        STAGE(gA, 0, 1, t1, nb);
        STAGE(gB, 16384, 1, t1, nb);
        VMCNT4();

        // ---- P1: MFMA (t).kh1; pre-read (t+1).kh0 from nb; stage (t+2).K0 -> b ----
        BARRIER();
        PHASE(aN, bN, nb, 0, aCur, bCur);
        STAGE(gA, 0, 0, t2, b);
        STAGE(gB, 16384, 0, t2, b);
        VMCNT4();
    };

    // ---- prologue: t0 both halves + t1.K0 (12 loads); vmcnt(4) retires t0 ----
    {
        STAGE(gA, 0, 0, 0, 0);       // t0.A.K0
        STAGE(gB, 16384, 0, 0, 0);   // t0.B.K0
        STAGE(gA, 0, 1, 0, 0);       // t0.A.K1
        STAGE(gB, 16384, 1, 0, 0);   // t0.B.K1
        STAGE(gA, 0, 0, 1, 1);       // t1.A.K0
        STAGE(gB, 16384, 0, 1, 1);   // t1.B.K0
        VMCNT4();                    // retires the 8 t0 loads; t1.K0 in flight
        BARRIER();
#pragma unroll
        for (int s = 0; s < 2; ++s) {
#pragma unroll
            for (int mt = 0; mt < 4; ++mt) LD_A32(0, 0, s, mt, aCur[s][mt]);
#pragma unroll
            for (int nt = 0; nt < 2; ++nt) LD_B32(0, 0, s, nt, bCur[s][nt]);
        }
    }

    for (int t = 0; t < nkt; t += 2) {
        KSTEP(t);
        KSTEP(t + 1);
    }

    // ---- epilogue: C = acc + bias (fp32). 32x32 C/D: col=lane&31,
    //      row = (reg&3) + 8*(reg>>2) + 4*(lane>>5)  [m74/m101 verified] ----
    const int r0 = bm * 256 + wr * 128;
    const int c0 = bn * 256 + wc * 64;
#pragma unroll
    for (int nt = 0; nt < 2; ++nt) {
        const int col = c0 + nt * 32 + (lane & 31);
        float bv = bias[col];
#pragma unroll
        for (int mt = 0; mt < 4; ++mt) {
#pragma unroll
            for (int r = 0; r < 16; ++r) {
                int row = r0 + mt * 32 + (r & 3) + 8 * (r >> 2) + 4 * (lane >> 5);
                C[(size_t)row * N + col] = acc[mt][nt][r] + bv;
            }
        }
    }
}

// ---- fallback (shape-generic, slow but correct) -----------------------------
__global__ void fallback_gemm(const float* __restrict__ x, const float* __restrict__ w,
                              const float* __restrict__ sinv, const float* __restrict__ bias,
                              float* __restrict__ out, int M, int N, int K) {
    int n = blockIdx.x * 64 + (threadIdx.x & 63);
    int m = blockIdx.y * 4 + (threadIdx.x >> 6);
    if (m >= M || n >= N) return;
    const int nbk = K >> 7;
    float acc = 0.f;
    for (int k = 0; k < K; ++k)
        acc += x[(size_t)m * K + k] * w[(size_t)n * K + k] * sinv[(n >> 7) * nbk + (k >> 7)];
    out[(size_t)m * N + n] = acc + bias[n];
}

extern "C" void kernel_launch(void* const* d_in, const int* in_sizes, int n_in,
                              void* d_out, int out_size, void* d_ws, size_t ws_size,
                              hipStream_t stream) {
    const float* x    = (const float*)d_in[0];
    const float* w    = (const float*)d_in[1];
    const float* sinv = (const float*)d_in[2];
    const float* bias = (const float*)d_in[3];
    float* out        = (float*)d_out;

    const int O = in_sizes[3];                  // 4096
    const int K = in_sizes[1] / O;              // 4096
    const int M = (int)((long)in_sizes[0] / K); // B*S = 4096
    const int N = O;

    const size_t need = ((size_t)M * K + (size_t)N * K) * sizeof(ushort);
    const int nwg = (M / 256) * (N / 256);
    const bool ok = ws_size >= need && (M % 256 == 0) && (N % 256 == 0) &&
                    (K % 128 == 0) && (nwg % 8 == 0) && ((long)M * K % 2048 == 0) &&
                    (K % 2048 == 0);
    if (ok) {
        ushort* xb = (ushort*)d_ws;
        ushort* wb = xb + (size_t)M * K;
        long n8x = (long)M * K / 8;
        long n8w = (long)N * K / 8;
        long n8m = (n8x > n8w) ? n8x : n8w;
        dim3 cg((unsigned)((n8m + 255) / 256), 2);
        conv_both_kernel<<<cg, 256, 0, stream>>>(x, xb, n8x, w, sinv, wb, K, K >> 7, n8w);
        gemm256_kernel<<<dim3(nwg), 512, 0, stream>>>(xb, wb, bias, out, M, N, K);
    } else {
        dim3 g(N / 64, (M + 3) / 4);
        fallback_gemm<<<g, 256, 0, stream>>>(x, w, sinv, bias, out, M, N, K);
    }
}